// Round 1
// baseline (1767.137 us; speedup 1.0000x reference)
//
#include <hip/hip_runtime.h>
#include <hip/hip_cooperative_groups.h>
#include <math.h>

namespace cg = cooperative_groups;

#define D 1024
#define LSEQ 256
#define NB 128
#define NTILE 1024   // per-phase tiles: gemm = 32 nb x 32 kb ; stream = 8 chunks x 128 b
constexpr float SCALE = 0.03125f; // 1/sqrt(1024)

struct Params {
  const float *ref, *cap, *tar;
  const float *qr_w, *qr_b, *ktxt_w, *ktxt_b, *ktar_w, *ktar_b, *v_w, *v_b;
  float *out, *ws;
};

struct SMem {
  union {
    struct { float As[32 * 132]; float Ws[32 * 36]; float rowf[128]; } g; // 22016 B
    struct { float nsh[4 * D]; float ssh[4]; } r;                          // 16400 B
  };
};

__device__ __forceinline__ float atomAdd(float* p, float v) {
  return unsafeAtomicAdd(p, v);  // HW global_atomic_add_f32; values are far from denormal
}

// ---------------- phase 0: zero all atomic accumulators ----------------
// ws layout: q0,p,nacc,u,w,accT (6 * NB*D) then sA[128], Z[128]; plus d_out.
__device__ __forceinline__ void phase_zero(const Params& P) {
  const size_t PS = (size_t)NB * D;
  const size_t nWs4 = 6 * PS / 4 + 64;   // 6 arrays + sA/Z (256 floats)
  const size_t nOut4 = PS / 4;
  const float4 z = make_float4(0.f, 0.f, 0.f, 0.f);
  for (size_t i = (size_t)blockIdx.x * 256 + threadIdx.x; i < nWs4 + nOut4;
       i += (size_t)gridDim.x * 256) {
    if (i < nWs4) ((float4*)P.ws)[i] = z;
    else ((float4*)P.out)[i - nWs4] = z;
  }
}

// ---------------- GEMM phase: C += A @ W(FORM), k-split 32, atomic merge ----------------
// Tiles: t in [0,1024): nbase=(t&31)*32, kb=t>>5 (32-wide k slice).
// FORM 0: C[m,n]+=sum_k A[m,k]*W[n,k] ; FORM 1: C[m,n]+=sum_k A[m,k]*W[k,n]
// BIASMODE (kb==0 only): 1 +bias[n]; 2 +rowS[m]*bias[n].  SCALEA: A rows scaled by 1/rowS[m].
template<int FORM, int BIASMODE, int SCALEA>
__device__ __forceinline__ void gemm_phase(
    const float* __restrict__ A, size_t lda,
    const float* __restrict__ W,
    const float* __restrict__ bias,
    const float* __restrict__ rowS,   // sA (BIASMODE2) or Z (SCALEA), final [128]
    float* __restrict__ C, SMem& sm) {
  float* As = sm.g.As;
  float* Ws = sm.g.Ws;
  const int tid = threadIdx.x;
  const int tm = tid & 31, tn = tid >> 5;
  if (SCALEA || BIASMODE == 2) {
    if (tid < 128) sm.g.rowf[tid] = SCALEA ? (1.f / rowS[tid]) : rowS[tid];
  }
  for (int t = blockIdx.x; t < NTILE; t += gridDim.x) {
    const int nbase = (t & 31) << 5;
    const int kc = (t >> 5) << 5;
    const int kb0 = (kc == 0);
    __syncthreads();  // LDS reuse guard; also publishes rowf on first iter
    // stage A: 128m x 32k (transposed into As[k][m], pad 132)
    #pragma unroll
    for (int i = 0; i < 4; ++i) {
      int f = tid + (i << 8);
      int m = f >> 3, kq = f & 7;
      float4 v = *(const float4*)(A + (size_t)m * lda + kc + (kq << 2));
      if (SCALEA) { float sc = sm.g.rowf[m]; v.x *= sc; v.y *= sc; v.z *= sc; v.w *= sc; }
      As[(kq * 4 + 0) * 132 + m] = v.x; As[(kq * 4 + 1) * 132 + m] = v.y;
      As[(kq * 4 + 2) * 132 + m] = v.z; As[(kq * 4 + 3) * 132 + m] = v.w;
    }
    // stage W: 32k x 32n into Ws[k][n], pad 36
    if (FORM == 1) {
      int kk = tid >> 3, nq = tid & 7;
      *(float4*)&Ws[kk * 36 + nq * 4] =
          *(const float4*)(W + (size_t)(kc + kk) * D + nbase + (nq << 2));
    } else {
      int n = tid >> 3, kq = tid & 7;
      float4 v = *(const float4*)(W + (size_t)(nbase + n) * D + kc + (kq << 2));
      Ws[(kq * 4 + 0) * 36 + n] = v.x; Ws[(kq * 4 + 1) * 36 + n] = v.y;
      Ws[(kq * 4 + 2) * 36 + n] = v.z; Ws[(kq * 4 + 3) * 36 + n] = v.w;
    }
    __syncthreads();
    float acc[4][4] = {{0.f, 0.f, 0.f, 0.f}, {0.f, 0.f, 0.f, 0.f},
                       {0.f, 0.f, 0.f, 0.f}, {0.f, 0.f, 0.f, 0.f}};
    #pragma unroll
    for (int kk = 0; kk < 32; ++kk) {
      float4 a4 = *(const float4*)&As[kk * 132 + tm * 4];
      float4 w4 = *(const float4*)&Ws[kk * 36 + tn * 4];
      float av[4] = {a4.x, a4.y, a4.z, a4.w};
      float wv[4] = {w4.x, w4.y, w4.z, w4.w};
      #pragma unroll
      for (int i2 = 0; i2 < 4; ++i2)
        #pragma unroll
        for (int j = 0; j < 4; ++j)
          acc[i2][j] = fmaf(av[i2], wv[j], acc[i2][j]);
    }
    #pragma unroll
    for (int i2 = 0; i2 < 4; ++i2) {
      int m = tm * 4 + i2, n = nbase + tn * 4;
      float4 st = make_float4(acc[i2][0], acc[i2][1], acc[i2][2], acc[i2][3]);
      if (kb0) {
        if (BIASMODE == 1) {
          st.x += bias[n]; st.y += bias[n + 1]; st.z += bias[n + 2]; st.w += bias[n + 3];
        } else if (BIASMODE == 2) {
          float rs = sm.g.rowf[m];
          st.x = fmaf(rs, bias[n],     st.x); st.y = fmaf(rs, bias[n + 1], st.y);
          st.z = fmaf(rs, bias[n + 2], st.z); st.w = fmaf(rs, bias[n + 3], st.w);
        }
      }
      float* dst = C + (size_t)m * D + n;
      atomAdd(dst + 0, st.x); atomAdd(dst + 1, st.y);
      atomAdd(dst + 2, st.z); atomAdd(dst + 3, st.w);
    }
  }
}

// ---------------- stream phase (cap: EXPMODE 0, tar: EXPMODE 1) ----------------
// Tiles: t in [0,1024): chunk=t>>7 (8 chunks of 32 rows), b=t&127.
// a = SCALE*(vecP[b].X[b,r] + vecQ[b].kbias); EXPMODE applies exp.
// accOut[b,:] += sum_r a*X[b,r,:]; sOut[b] += sum_r a.   (atomic merge of 8 chunks)
template<int EXPMODE>
__device__ __forceinline__ void stream_phase(
    const float* __restrict__ X,
    const float* __restrict__ vecP,
    const float* __restrict__ vecQ,
    const float* __restrict__ kbias,
    float* __restrict__ accOut,
    float* __restrict__ sOut, SMem& sm) {
  const int tid = threadIdx.x;
  const int wid = tid >> 6, lane = tid & 63;
  for (int t = blockIdx.x; t < NTILE; t += gridDim.x) {
    const int chunk = t >> 7, b = t & 127;
    float4 p4[4], acc[4];
    float qloc = 0.f;
    #pragma unroll
    for (int s = 0; s < 4; ++s) {
      int d = s * 256 + lane * 4;
      p4[s] = *(const float4*)(vecP + (size_t)b * D + d);
      float4 qv = *(const float4*)(vecQ + (size_t)b * D + d);
      float4 kb4 = *(const float4*)(kbias + d);
      acc[s] = make_float4(0.f, 0.f, 0.f, 0.f);
      qloc = fmaf(qv.x, kb4.x, qloc); qloc = fmaf(qv.y, kb4.y, qloc);
      qloc = fmaf(qv.z, kb4.z, qloc); qloc = fmaf(qv.w, kb4.w, qloc);
    }
    #pragma unroll
    for (int off = 32; off; off >>= 1) qloc += __shfl_xor(qloc, off);
    const float qd = qloc;  // full 1024-dot per wave

    float sAw = 0.f;
    const float* Xb = X + (size_t)b * LSEQ * D;
    const int r0 = chunk * 32 + wid;
    float4 r4[4], r4n[4];
    {
      const float* row = Xb + (size_t)r0 * D;
      #pragma unroll
      for (int s = 0; s < 4; ++s) r4[s] = *(const float4*)(row + s * 256 + lane * 4);
    }
    for (int i = 0; i < 8; ++i) {
      if (i < 7) {
        const float* row = Xb + (size_t)(r0 + (i + 1) * 4) * D;
        #pragma unroll
        for (int s = 0; s < 4; ++s) r4n[s] = *(const float4*)(row + s * 256 + lane * 4);
      }
      float tt = 0.f;
      #pragma unroll
      for (int s = 0; s < 4; ++s) {
        tt = fmaf(p4[s].x, r4[s].x, tt); tt = fmaf(p4[s].y, r4[s].y, tt);
        tt = fmaf(p4[s].z, r4[s].z, tt); tt = fmaf(p4[s].w, r4[s].w, tt);
      }
      #pragma unroll
      for (int off = 32; off; off >>= 1) tt += __shfl_xor(tt, off);
      float a;
      if (EXPMODE) a = expf(SCALE * (tt + qd));
      else         a = SCALE * (tt + qd);
      sAw += a;
      #pragma unroll
      for (int s = 0; s < 4; ++s) {
        acc[s].x = fmaf(a, r4[s].x, acc[s].x); acc[s].y = fmaf(a, r4[s].y, acc[s].y);
        acc[s].z = fmaf(a, r4[s].z, acc[s].z); acc[s].w = fmaf(a, r4[s].w, acc[s].w);
      }
      #pragma unroll
      for (int s = 0; s < 4; ++s) r4[s] = r4n[s];
    }
    __syncthreads();  // LDS reuse guard (prev tile / prev phase)
    #pragma unroll
    for (int s = 0; s < 4; ++s)
      *(float4*)&sm.r.nsh[wid * D + s * 256 + lane * 4] = acc[s];
    if (lane == 0) sm.r.ssh[wid] = sAw;
    __syncthreads();
    float4 v = make_float4(0.f, 0.f, 0.f, 0.f);
    #pragma unroll
    for (int ww = 0; ww < 4; ++ww) {
      float4 x = *(const float4*)&sm.r.nsh[ww * D + tid * 4];
      v.x += x.x; v.y += x.y; v.z += x.z; v.w += x.w;
    }
    float* dst = accOut + (size_t)b * D + tid * 4;
    atomAdd(dst + 0, v.x); atomAdd(dst + 1, v.y);
    atomAdd(dst + 2, v.z); atomAdd(dst + 3, v.w);
    if (tid == 0)
      atomAdd(sOut + b, sm.r.ssh[0] + sm.r.ssh[1] + sm.r.ssh[2] + sm.r.ssh[3]);
  }
}

// ---------------- shared phase dispatcher ----------------
__device__ __forceinline__ void run_phase(int ph, const Params& P, SMem& sm) {
  const size_t PS = (size_t)NB * D;
  float* q0   = P.ws;
  float* p    = P.ws + PS;
  float* nacc = P.ws + 2 * PS;
  float* u    = P.ws + 3 * PS;
  float* w    = P.ws + 4 * PS;
  float* accT = P.ws + 5 * PS;
  float* sA   = P.ws + 6 * PS;
  float* Z    = sA + NB;
  switch (ph) {
    case 0: phase_zero(P); break;
    case 1: gemm_phase<0, 1, 0>(P.ref, (size_t)LSEQ * D, P.qr_w, P.qr_b, nullptr, q0, sm); break;
    case 2: gemm_phase<1, 0, 0>(q0, D, P.ktxt_w, nullptr, nullptr, p, sm); break;
    case 3: stream_phase<0>(P.cap, p, q0, P.ktxt_b, nacc, sA, sm); break;
    case 4: gemm_phase<0, 2, 0>(nacc, D, P.ktxt_w, P.ktxt_b, sA, u, sm); break;
    case 5: gemm_phase<1, 0, 0>(u, D, P.ktar_w, nullptr, nullptr, w, sm); break;
    case 6: stream_phase<1>(P.tar, w, u, P.ktar_b, accT, Z, sm); break;
    case 7: gemm_phase<0, 1, 1>(accT, D, P.v_w, P.v_b, Z, P.out, sm); break;
  }
}

// ---------------- fused cooperative kernel ----------------
__global__ __launch_bounds__(256, 4) void fused_kernel(Params P) {
  __shared__ SMem sm;
  cg::grid_group grid = cg::this_grid();
  #pragma unroll
  for (int ph = 0; ph < 8; ++ph) {
    if (ph) grid.sync();
    run_phase(ph, P, sm);
  }
}

// ---------------- fallback: one regular launch per phase ----------------
__global__ __launch_bounds__(256, 4) void phase_kernel(Params P, int ph) {
  __shared__ SMem sm;
  run_phase(ph, P, sm);
}

extern "C" void kernel_launch(void* const* d_in, const int* in_sizes, int n_in,
                              void* d_out, int out_size, void* d_ws, size_t ws_size,
                              hipStream_t stream) {
  Params prm;
  prm.ref    = (const float*)d_in[0];
  prm.cap    = (const float*)d_in[1];
  prm.tar    = (const float*)d_in[2];
  prm.qr_w   = (const float*)d_in[3];
  prm.qr_b   = (const float*)d_in[4];
  prm.ktxt_w = (const float*)d_in[5];
  prm.ktxt_b = (const float*)d_in[6];
  prm.ktar_w = (const float*)d_in[7];
  prm.ktar_b = (const float*)d_in[8];
  prm.v_w    = (const float*)d_in[9];
  prm.v_b    = (const float*)d_in[10];
  prm.out    = (float*)d_out;
  prm.ws     = (float*)d_ws;

  // Grid sized by occupancy so all blocks are co-resident (grid-stride loops make
  // any grid <= NTILE correct). Cached across calls; pure queries, capture-safe.
  static int grid = -1;
  if (grid < 0) {
    int occ = 0, nCU = 0;
    (void)hipOccupancyMaxActiveBlocksPerMultiprocessor(&occ, fused_kernel, 256, 0);
    (void)hipDeviceGetAttribute(&nCU, hipDeviceAttributeMultiprocessorCount, 0);
    if (occ < 1) occ = 1;
    if (nCU < 1) nCU = 256;
    long g = (long)occ * (long)nCU;
    grid = (int)(g > NTILE ? NTILE : g);
  }

  void* kargs[] = { (void*)&prm };
  hipError_t e = hipLaunchCooperativeKernel((const void*)fused_kernel,
                                            dim3(grid), dim3(256), kargs, 0u, stream);
  if (e != hipSuccess) {
    (void)hipGetLastError();  // clear; fall back to 8 plain launches (stream-ordered)
    for (int ph = 0; ph < 8; ++ph)
      hipLaunchKernelGGL(phase_kernel, dim3(NTILE), dim3(256), 0, stream, prm, ph);
  }
}

// Round 2
// 1282.538 us; speedup vs baseline: 1.3778x; 1.3778x over previous
//
#include <hip/hip_runtime.h>
#include <hip/hip_cooperative_groups.h>
#include <math.h>

namespace cg = cooperative_groups;

#define D 1024
#define LSEQ 256
#define NB 128
#define NTILE 1024
#define PS ((size_t)NB * D)      // 131072 floats per [128,1024] array
constexpr float SCALE = 0.03125f; // 1/sqrt(1024)

struct Params {
  const float *ref, *cap, *tar;
  const float *qr_w, *qr_b, *ktxt_w, *ktxt_b, *ktar_w, *ktar_b, *v_w, *v_b;
  float *out, *ws;
};

struct SMem {
  union {
    struct { float As[32 * 132]; float Ws[32 * 36]; float rowf[128]; } g; // 22016 B
    struct { float nsh[4 * D]; float ssh[4]; } r;                          // 16400 B
  };
};

// ---------------- GEMM phase: k-split 32, plain coalesced permuted stores ----
// 1024 tiles: nb = t&31 (32-col slab), ks = t>>5 (32-wide k slice).
// FORM 0: C[m,n]+=sum_k A[m,k]*W[n,k] ; FORM 1: C[m,n]+=sum_k A[m,k]*W[k,n]
// BIASMODE (ks==0 tile only): 1 +bias[n]; 2 +rowS[m]*bias[n].
// SCALEA: A rows scaled by 1/rowS[m] at staging.
// Partial layout (coalesced store): phys = ks*PS + nb*4096 + i2*1024 + tid*4 + c
// where logical m = (tid&31)*4 + i2, n = nb*32 + (tid>>5)*4 + c.
template<int FORM, int BIASMODE, int SCALEA>
__device__ __forceinline__ void gemm_phase(
    const float* __restrict__ A, size_t lda,
    const float* __restrict__ W,
    const float* __restrict__ bias,
    const float* __restrict__ rowS,
    float* __restrict__ Cpart, SMem& sm) {
  const int tid = threadIdx.x;
  const int tm = tid & 31, tn = tid >> 5;
  if ((SCALEA || BIASMODE == 2) && tid < 128)
    sm.g.rowf[tid] = SCALEA ? (1.f / rowS[tid]) : rowS[tid];
  for (int t = blockIdx.x; t < NTILE; t += gridDim.x) {
    const int nb = t & 31, ks = t >> 5;
    const int nbase = nb << 5, kc = ks << 5;
    __syncthreads();  // LDS reuse guard; publishes rowf on first iter
    // stage A: 128m x 32k into As[k][m] (pad 132)
    #pragma unroll
    for (int i = 0; i < 4; ++i) {
      int f = tid + (i << 8);
      int m = f >> 3, kq = f & 7;
      float4 v = *(const float4*)(A + (size_t)m * lda + kc + (kq << 2));
      if (SCALEA) { float sc = sm.g.rowf[m]; v.x *= sc; v.y *= sc; v.z *= sc; v.w *= sc; }
      sm.g.As[(kq * 4 + 0) * 132 + m] = v.x; sm.g.As[(kq * 4 + 1) * 132 + m] = v.y;
      sm.g.As[(kq * 4 + 2) * 132 + m] = v.z; sm.g.As[(kq * 4 + 3) * 132 + m] = v.w;
    }
    // stage W: 32k x 32n into Ws[k][n] (pad 36)
    if (FORM == 1) {
      int kk = tid >> 3, nq = tid & 7;
      *(float4*)&sm.g.Ws[kk * 36 + nq * 4] =
          *(const float4*)(W + (size_t)(kc + kk) * D + nbase + (nq << 2));
    } else {
      int n = tid >> 3, kq = tid & 7;
      float4 v = *(const float4*)(W + (size_t)(nbase + n) * D + kc + (kq << 2));
      sm.g.Ws[(kq * 4 + 0) * 36 + n] = v.x; sm.g.Ws[(kq * 4 + 1) * 36 + n] = v.y;
      sm.g.Ws[(kq * 4 + 2) * 36 + n] = v.z; sm.g.Ws[(kq * 4 + 3) * 36 + n] = v.w;
    }
    __syncthreads();
    float acc[4][4] = {{0.f, 0.f, 0.f, 0.f}, {0.f, 0.f, 0.f, 0.f},
                       {0.f, 0.f, 0.f, 0.f}, {0.f, 0.f, 0.f, 0.f}};
    #pragma unroll
    for (int kk = 0; kk < 32; ++kk) {
      float4 a4 = *(const float4*)&sm.g.As[kk * 132 + tm * 4];
      float4 w4 = *(const float4*)&sm.g.Ws[kk * 36 + tn * 4];
      float av[4] = {a4.x, a4.y, a4.z, a4.w};
      float wv[4] = {w4.x, w4.y, w4.z, w4.w};
      #pragma unroll
      for (int i2 = 0; i2 < 4; ++i2)
        #pragma unroll
        for (int j = 0; j < 4; ++j)
          acc[i2][j] = fmaf(av[i2], wv[j], acc[i2][j]);
    }
    if (BIASMODE && ks == 0) {
      #pragma unroll
      for (int i2 = 0; i2 < 4; ++i2) {
        int m = tm * 4 + i2, n = nbase + tn * 4;
        if (BIASMODE == 1) {
          acc[i2][0] += bias[n];     acc[i2][1] += bias[n + 1];
          acc[i2][2] += bias[n + 2]; acc[i2][3] += bias[n + 3];
        } else {
          float rs = sm.g.rowf[m];
          acc[i2][0] = fmaf(rs, bias[n],     acc[i2][0]);
          acc[i2][1] = fmaf(rs, bias[n + 1], acc[i2][1]);
          acc[i2][2] = fmaf(rs, bias[n + 2], acc[i2][2]);
          acc[i2][3] = fmaf(rs, bias[n + 3], acc[i2][3]);
        }
      }
    }
    // fully coalesced permuted partial store (no atomics)
    float* Cout = Cpart + (size_t)ks * PS + (size_t)nb * 4096;
    #pragma unroll
    for (int i2 = 0; i2 < 4; ++i2)
      *(float4*)(Cout + (size_t)(i2 * 256 + tid) * 4) =
          make_float4(acc[i2][0], acc[i2][1], acc[i2][2], acc[i2][3]);
  }
}

// ---------------- reduce 32 permuted partials -> standard [m][n] ------------
__device__ __forceinline__ void reduce32perm(const float* __restrict__ src,
                                             float* __restrict__ dst) {
  for (int i = blockIdx.x * 256 + threadIdx.x; i < (int)PS;
       i += gridDim.x * 256) {
    float s = 0.f;
    #pragma unroll
    for (int p = 0; p < 32; ++p) s += src[(size_t)p * PS + i];
    int nb = i >> 12, i2 = (i >> 10) & 3, tn = (i >> 7) & 7;
    int tm = (i >> 2) & 31, c = i & 3;
    int m = tm * 4 + i2, n = nb * 32 + tn * 4 + c;
    dst[(size_t)m * D + n] = s;
  }
}

// ---------------- reduce 8 standard partials + 128 scalars ------------------
__device__ __forceinline__ void reduce8(const float* __restrict__ src,
                                        float* __restrict__ dst,
                                        const float* __restrict__ sSrc,
                                        float* __restrict__ sDst) {
  const int total = (int)PS + 128;
  for (int i = blockIdx.x * 256 + threadIdx.x; i < total; i += gridDim.x * 256) {
    if (i < (int)PS) {
      float s = 0.f;
      #pragma unroll
      for (int p = 0; p < 8; ++p) s += src[(size_t)p * PS + i];
      dst[i] = s;
    } else {
      int m = i - (int)PS;
      float s = 0.f;
      #pragma unroll
      for (int p = 0; p < 8; ++p) s += sSrc[p * 128 + m];
      sDst[m] = s;
    }
  }
}

// ---------------- stream phase (cap EXPMODE 0 / tar EXPMODE 1) --------------
// 1024 tiles: chunk = t>>7 (8 x 32 rows), b = t&127. Plain partial stores.
template<int EXPMODE>
__device__ __forceinline__ void stream_phase(
    const float* __restrict__ X,
    const float* __restrict__ vecP,
    const float* __restrict__ vecQ,
    const float* __restrict__ kbias,
    float* __restrict__ accOut,   // [8][128][1024]
    float* __restrict__ sOut,     // [8][128]
    SMem& sm) {
  const int tid = threadIdx.x;
  const int wid = tid >> 6, lane = tid & 63;
  for (int t = blockIdx.x; t < NTILE; t += gridDim.x) {
    const int chunk = t >> 7, b = t & 127;
    float4 p4[4], acc[4];
    float qloc = 0.f;
    #pragma unroll
    for (int s = 0; s < 4; ++s) {
      int d = s * 256 + lane * 4;
      p4[s] = *(const float4*)(vecP + (size_t)b * D + d);
      float4 qv = *(const float4*)(vecQ + (size_t)b * D + d);
      float4 kb4 = *(const float4*)(kbias + d);
      acc[s] = make_float4(0.f, 0.f, 0.f, 0.f);
      qloc = fmaf(qv.x, kb4.x, qloc); qloc = fmaf(qv.y, kb4.y, qloc);
      qloc = fmaf(qv.z, kb4.z, qloc); qloc = fmaf(qv.w, kb4.w, qloc);
    }
    #pragma unroll
    for (int off = 32; off; off >>= 1) qloc += __shfl_xor(qloc, off);
    const float qd = qloc;

    float sAw = 0.f;
    const float* Xb = X + (size_t)b * LSEQ * D;
    const int r0 = chunk * 32 + wid;
    float4 r4[4], r4n[4];
    {
      const float* row = Xb + (size_t)r0 * D;
      #pragma unroll
      for (int s = 0; s < 4; ++s) r4[s] = *(const float4*)(row + s * 256 + lane * 4);
    }
    for (int i = 0; i < 8; ++i) {
      if (i < 7) {
        const float* row = Xb + (size_t)(r0 + (i + 1) * 4) * D;
        #pragma unroll
        for (int s = 0; s < 4; ++s) r4n[s] = *(const float4*)(row + s * 256 + lane * 4);
      }
      float tt = 0.f;
      #pragma unroll
      for (int s = 0; s < 4; ++s) {
        tt = fmaf(p4[s].x, r4[s].x, tt); tt = fmaf(p4[s].y, r4[s].y, tt);
        tt = fmaf(p4[s].z, r4[s].z, tt); tt = fmaf(p4[s].w, r4[s].w, tt);
      }
      #pragma unroll
      for (int off = 32; off; off >>= 1) tt += __shfl_xor(tt, off);
      float a;
      if (EXPMODE) a = expf(SCALE * (tt + qd));
      else         a = SCALE * (tt + qd);
      sAw += a;
      #pragma unroll
      for (int s = 0; s < 4; ++s) {
        acc[s].x = fmaf(a, r4[s].x, acc[s].x); acc[s].y = fmaf(a, r4[s].y, acc[s].y);
        acc[s].z = fmaf(a, r4[s].z, acc[s].z); acc[s].w = fmaf(a, r4[s].w, acc[s].w);
      }
      #pragma unroll
      for (int s = 0; s < 4; ++s) r4[s] = r4n[s];
    }
    __syncthreads();  // LDS reuse guard
    #pragma unroll
    for (int s = 0; s < 4; ++s)
      *(float4*)&sm.r.nsh[wid * D + s * 256 + lane * 4] = acc[s];
    if (lane == 0) sm.r.ssh[wid] = sAw;
    __syncthreads();
    float4 v = make_float4(0.f, 0.f, 0.f, 0.f);
    #pragma unroll
    for (int ww = 0; ww < 4; ++ww) {
      float4 x = *(const float4*)&sm.r.nsh[ww * D + tid * 4];
      v.x += x.x; v.y += x.y; v.z += x.z; v.w += x.w;
    }
    *(float4*)(accOut + ((size_t)chunk * NB + b) * D + tid * 4) = v;
    if (tid == 0)
      sOut[chunk * NB + b] = sm.r.ssh[0] + sm.r.ssh[1] + sm.r.ssh[2] + sm.r.ssh[3];
  }
}

// ---------------- buffers (24 MB of ws; big/strm regions reused) ------------
struct Bufs {
  float *big;   // 32*PS : q0part/ppart/upart/wpart/outPart (serial reuse)
  float *strm;  //  8*PS : naccP/accP (serial reuse)
  float *q0, *p, *nacc, *u, *w, *accT;  // finals, 1*PS each
  float *sAP, *sA, *ZP, *Z;
};
__device__ __forceinline__ Bufs get_bufs(float* ws) {
  Bufs b;
  b.big  = ws;
  b.strm = ws + 32 * PS;
  b.q0   = ws + 40 * PS;
  b.p    = ws + 41 * PS;
  b.nacc = ws + 42 * PS;
  b.u    = ws + 43 * PS;
  b.w    = ws + 44 * PS;
  b.accT = ws + 45 * PS;
  b.sAP  = ws + 46 * PS;
  b.sA   = b.sAP + 1024;
  b.ZP   = b.sA + 128;
  b.Z    = b.ZP + 1024;
  return b;
}

__device__ __forceinline__ void run_phase(int ph, const Params& P, SMem& sm) {
  Bufs b = get_bufs(P.ws);
  switch (ph) {
    case 0:  gemm_phase<0, 1, 0>(P.ref, (size_t)LSEQ * D, P.qr_w, P.qr_b, nullptr, b.big, sm); break;
    case 1:  reduce32perm(b.big, b.q0); break;
    case 2:  gemm_phase<1, 0, 0>(b.q0, D, P.ktxt_w, nullptr, nullptr, b.big, sm); break;
    case 3:  reduce32perm(b.big, b.p); break;
    case 4:  stream_phase<0>(P.cap, b.p, b.q0, P.ktxt_b, b.strm, b.sAP, sm); break;
    case 5:  reduce8(b.strm, b.nacc, b.sAP, b.sA); break;
    case 6:  gemm_phase<0, 2, 0>(b.nacc, D, P.ktxt_w, P.ktxt_b, b.sA, b.big, sm); break;
    case 7:  reduce32perm(b.big, b.u); break;
    case 8:  gemm_phase<1, 0, 0>(b.u, D, P.ktar_w, nullptr, nullptr, b.big, sm); break;
    case 9:  reduce32perm(b.big, b.w); break;
    case 10: stream_phase<1>(P.tar, b.w, b.u, P.ktar_b, b.strm, b.ZP, sm); break;
    case 11: reduce8(b.strm, b.accT, b.ZP, b.Z); break;
    case 12: gemm_phase<0, 1, 1>(b.accT, D, P.v_w, P.v_b, b.Z, b.big, sm); break;
    case 13: reduce32perm(b.big, P.out); break;
  }
}

// ---------------- fused cooperative kernel ----------------
__global__ __launch_bounds__(256, 4) void fused_kernel(Params P) {
  __shared__ SMem sm;
  cg::grid_group grid = cg::this_grid();
  for (int ph = 0; ph < 14; ++ph) {
    if (ph) grid.sync();
    run_phase(ph, P, sm);
  }
}

// ---------------- fallback: one regular launch per phase ----------------
__global__ __launch_bounds__(256, 4) void phase_kernel(Params P, int ph) {
  __shared__ SMem sm;
  run_phase(ph, P, sm);
}

extern "C" void kernel_launch(void* const* d_in, const int* in_sizes, int n_in,
                              void* d_out, int out_size, void* d_ws, size_t ws_size,
                              hipStream_t stream) {
  Params prm;
  prm.ref    = (const float*)d_in[0];
  prm.cap    = (const float*)d_in[1];
  prm.tar    = (const float*)d_in[2];
  prm.qr_w   = (const float*)d_in[3];
  prm.qr_b   = (const float*)d_in[4];
  prm.ktxt_w = (const float*)d_in[5];
  prm.ktxt_b = (const float*)d_in[6];
  prm.ktar_w = (const float*)d_in[7];
  prm.ktar_b = (const float*)d_in[8];
  prm.v_w    = (const float*)d_in[9];
  prm.v_b    = (const float*)d_in[10];
  prm.out    = (float*)d_out;
  prm.ws     = (float*)d_ws;

  static int grid = -1;
  if (grid < 0) {
    int occ = 0, nCU = 0;
    (void)hipOccupancyMaxActiveBlocksPerMultiprocessor(&occ, fused_kernel, 256, 0);
    (void)hipDeviceGetAttribute(&nCU, hipDeviceAttributeMultiprocessorCount, 0);
    if (occ < 1) occ = 1;
    if (nCU < 1) nCU = 256;
    long g = (long)occ * (long)nCU;
    grid = (int)(g > NTILE ? NTILE : g);
  }

  void* kargs[] = { (void*)&prm };
  hipError_t e = hipLaunchCooperativeKernel((const void*)fused_kernel,
                                            dim3(grid), dim3(256), kargs, 0u, stream);
  if (e != hipSuccess) {
    (void)hipGetLastError();  // clear; fall back to 14 plain launches
    for (int ph = 0; ph < 14; ++ph)
      hipLaunchKernelGGL(phase_kernel, dim3(NTILE), dim3(256), 0, stream, prm, ph);
  }
}

// Round 3
// 466.968 us; speedup vs baseline: 3.7843x; 2.7465x over previous
//
#include <hip/hip_runtime.h>
#include <math.h>

#define D 1024
#define LSEQ 256
#define NB 128
#define NTILE 1024
#define PS ((size_t)NB * D)      // 131072 floats per [128,1024] array
constexpr float SCALE = 0.03125f; // 1/sqrt(1024)

struct SMem {
  union {
    struct { float As[32 * 132]; float Ws[32 * 36]; float rowf[128]; } g; // 22016 B
    struct { float nsh[4 * D]; float ssh[4]; } r;                          // 16400 B
  };
};

// ---------------- GEMM: k-split 32, coalesced permuted partial stores -------
// grid 1024: nb = bid&31 (32-col slab), ks = bid>>5 (32-wide k slice).
// FORM 0: C[m,n]+=sum_k A[m,k]*W[n,k] ; FORM 1: C[m,n]+=sum_k A[m,k]*W[k,n]
// BIASMODE (ks==0): 1 +bias[n]; 2 +rowS[m]*bias[n]. SCALEA: A rows /rowS[m].
// Partial layout: phys = ks*PS + nb*4096 + i2*1024 + tid*4 + c
//   (logical m = (tid&31)*4 + i2, n = nb*32 + (tid>>5)*4 + c)
template<int FORM, int BIASMODE, int SCALEA>
__global__ __launch_bounds__(256, 4) void gemm_k(
    const float* __restrict__ A, size_t lda,
    const float* __restrict__ W,
    const float* __restrict__ bias,
    const float* __restrict__ rowS,
    float* __restrict__ Cpart) {
  __shared__ SMem sm;
  const int tid = threadIdx.x;
  const int tm = tid & 31, tn = tid >> 5;
  const int nb = blockIdx.x & 31, ks = blockIdx.x >> 5;
  const int nbase = nb << 5, kc = ks << 5;
  if ((SCALEA || BIASMODE == 2) && tid < 128)
    sm.g.rowf[tid] = SCALEA ? (1.f / rowS[tid]) : rowS[tid];
  if (SCALEA || BIASMODE == 2) __syncthreads();  // publish rowf
  // stage A: 128m x 32k into As[k][m] (pad 132)
  #pragma unroll
  for (int i = 0; i < 4; ++i) {
    int f = tid + (i << 8);
    int m = f >> 3, kq = f & 7;
    float4 v = *(const float4*)(A + (size_t)m * lda + kc + (kq << 2));
    if (SCALEA) { float sc = sm.g.rowf[m]; v.x *= sc; v.y *= sc; v.z *= sc; v.w *= sc; }
    sm.g.As[(kq * 4 + 0) * 132 + m] = v.x; sm.g.As[(kq * 4 + 1) * 132 + m] = v.y;
    sm.g.As[(kq * 4 + 2) * 132 + m] = v.z; sm.g.As[(kq * 4 + 3) * 132 + m] = v.w;
  }
  // stage W: 32k x 32n into Ws[k][n] (pad 36)
  if (FORM == 1) {
    int kk = tid >> 3, nq = tid & 7;
    *(float4*)&sm.g.Ws[kk * 36 + nq * 4] =
        *(const float4*)(W + (size_t)(kc + kk) * D + nbase + (nq << 2));
  } else {
    int n = tid >> 3, kq = tid & 7;
    float4 v = *(const float4*)(W + (size_t)(nbase + n) * D + kc + (kq << 2));
    sm.g.Ws[(kq * 4 + 0) * 36 + n] = v.x; sm.g.Ws[(kq * 4 + 1) * 36 + n] = v.y;
    sm.g.Ws[(kq * 4 + 2) * 36 + n] = v.z; sm.g.Ws[(kq * 4 + 3) * 36 + n] = v.w;
  }
  __syncthreads();
  float acc[4][4] = {{0.f, 0.f, 0.f, 0.f}, {0.f, 0.f, 0.f, 0.f},
                     {0.f, 0.f, 0.f, 0.f}, {0.f, 0.f, 0.f, 0.f}};
  #pragma unroll
  for (int kk = 0; kk < 32; ++kk) {
    float4 a4 = *(const float4*)&sm.g.As[kk * 132 + tm * 4];
    float4 w4 = *(const float4*)&sm.g.Ws[kk * 36 + tn * 4];
    float av[4] = {a4.x, a4.y, a4.z, a4.w};
    float wv[4] = {w4.x, w4.y, w4.z, w4.w};
    #pragma unroll
    for (int i2 = 0; i2 < 4; ++i2)
      #pragma unroll
      for (int j = 0; j < 4; ++j)
        acc[i2][j] = fmaf(av[i2], wv[j], acc[i2][j]);
  }
  if (BIASMODE && ks == 0) {
    #pragma unroll
    for (int i2 = 0; i2 < 4; ++i2) {
      int m = tm * 4 + i2, n = nbase + tn * 4;
      if (BIASMODE == 1) {
        acc[i2][0] += bias[n];     acc[i2][1] += bias[n + 1];
        acc[i2][2] += bias[n + 2]; acc[i2][3] += bias[n + 3];
      } else {
        float rs = sm.g.rowf[m];
        acc[i2][0] = fmaf(rs, bias[n],     acc[i2][0]);
        acc[i2][1] = fmaf(rs, bias[n + 1], acc[i2][1]);
        acc[i2][2] = fmaf(rs, bias[n + 2], acc[i2][2]);
        acc[i2][3] = fmaf(rs, bias[n + 3], acc[i2][3]);
      }
    }
  }
  float* Cout = Cpart + (size_t)ks * PS + (size_t)nb * 4096;
  #pragma unroll
  for (int i2 = 0; i2 < 4; ++i2)
    *(float4*)(Cout + (size_t)(i2 * 256 + tid) * 4) =
        make_float4(acc[i2][0], acc[i2][1], acc[i2][2], acc[i2][3]);
}

// ---------------- reduce 32 permuted partials -> standard [m][n], float4 ----
// grid 128 x 256: j in [0,32768) float4 ids. j = nb*1024 + i2*256 + tn*32 + tm.
__global__ __launch_bounds__(256, 4) void reduce32_k(
    const float* __restrict__ src, float* __restrict__ dst) {
  const int j = blockIdx.x * 256 + threadIdx.x;
  const float4* s4 = (const float4*)src;
  float4 v = s4[j];
  #pragma unroll
  for (int p = 1; p < 32; ++p) {
    float4 x = s4[(size_t)p * (PS / 4) + j];
    v.x += x.x; v.y += x.y; v.z += x.z; v.w += x.w;
  }
  int tm = j & 31, tn = (j >> 5) & 7, i2 = (j >> 8) & 3, nb = j >> 10;
  int m = tm * 4 + i2, n = nb * 32 + tn * 4;
  *(float4*)(dst + (size_t)m * D + n) = v;
}

// ---------------- reduce 8 standard partials + 128 scalars, float4 ----------
// grid 129: blocks 0..127 vectors, block 128 scalars.
__global__ __launch_bounds__(256, 4) void reduce8_k(
    const float* __restrict__ src, float* __restrict__ dst,
    const float* __restrict__ sSrc, float* __restrict__ sDst) {
  if (blockIdx.x < 128) {
    const int j = blockIdx.x * 256 + threadIdx.x;
    const float4* s4 = (const float4*)src;
    float4 v = s4[j];
    #pragma unroll
    for (int p = 1; p < 8; ++p) {
      float4 x = s4[(size_t)p * (PS / 4) + j];
      v.x += x.x; v.y += x.y; v.z += x.z; v.w += x.w;
    }
    ((float4*)dst)[j] = v;
  } else if (threadIdx.x < 128) {
    int m = threadIdx.x;
    float s = 0.f;
    #pragma unroll
    for (int p = 0; p < 8; ++p) s += sSrc[p * 128 + m];
    sDst[m] = s;
  }
}

// ---------------- stream (cap EXPMODE 0 / tar EXPMODE 1) --------------------
// grid 1024: chunk = bid>>7 (8 x 32 rows), b = bid&127. Plain partial stores.
template<int EXPMODE>
__global__ __launch_bounds__(256, 4) void stream_k(
    const float* __restrict__ X,
    const float* __restrict__ vecP,
    const float* __restrict__ vecQ,
    const float* __restrict__ kbias,
    float* __restrict__ accOut,   // [8][128][1024]
    float* __restrict__ sOut) {   // [8][128]
  __shared__ SMem sm;
  const int tid = threadIdx.x;
  const int wid = tid >> 6, lane = tid & 63;
  const int chunk = blockIdx.x >> 7, b = blockIdx.x & 127;
  float4 p4[4], acc[4];
  float qloc = 0.f;
  #pragma unroll
  for (int s = 0; s < 4; ++s) {
    int d = s * 256 + lane * 4;
    p4[s] = *(const float4*)(vecP + (size_t)b * D + d);
    float4 qv = *(const float4*)(vecQ + (size_t)b * D + d);
    float4 kb4 = *(const float4*)(kbias + d);
    acc[s] = make_float4(0.f, 0.f, 0.f, 0.f);
    qloc = fmaf(qv.x, kb4.x, qloc); qloc = fmaf(qv.y, kb4.y, qloc);
    qloc = fmaf(qv.z, kb4.z, qloc); qloc = fmaf(qv.w, kb4.w, qloc);
  }
  #pragma unroll
  for (int off = 32; off; off >>= 1) qloc += __shfl_xor(qloc, off);
  const float qd = qloc;  // full 1024-dot per wave

  float sAw = 0.f;
  const float* Xb = X + (size_t)b * LSEQ * D;
  const int r0 = chunk * 32 + wid;
  float4 r4[4], r4n[4];
  {
    const float* row = Xb + (size_t)r0 * D;
    #pragma unroll
    for (int s = 0; s < 4; ++s) r4[s] = *(const float4*)(row + s * 256 + lane * 4);
  }
  for (int i = 0; i < 8; ++i) {
    if (i < 7) {
      const float* row = Xb + (size_t)(r0 + (i + 1) * 4) * D;
      #pragma unroll
      for (int s = 0; s < 4; ++s) r4n[s] = *(const float4*)(row + s * 256 + lane * 4);
    }
    float tt = 0.f;
    #pragma unroll
    for (int s = 0; s < 4; ++s) {
      tt = fmaf(p4[s].x, r4[s].x, tt); tt = fmaf(p4[s].y, r4[s].y, tt);
      tt = fmaf(p4[s].z, r4[s].z, tt); tt = fmaf(p4[s].w, r4[s].w, tt);
    }
    #pragma unroll
    for (int off = 32; off; off >>= 1) tt += __shfl_xor(tt, off);
    float a;
    if (EXPMODE) a = expf(SCALE * (tt + qd));
    else         a = SCALE * (tt + qd);
    sAw += a;
    #pragma unroll
    for (int s = 0; s < 4; ++s) {
      acc[s].x = fmaf(a, r4[s].x, acc[s].x); acc[s].y = fmaf(a, r4[s].y, acc[s].y);
      acc[s].z = fmaf(a, r4[s].z, acc[s].z); acc[s].w = fmaf(a, r4[s].w, acc[s].w);
    }
    #pragma unroll
    for (int s = 0; s < 4; ++s) r4[s] = r4n[s];
  }
  #pragma unroll
  for (int s = 0; s < 4; ++s)
    *(float4*)&sm.r.nsh[wid * D + s * 256 + lane * 4] = acc[s];
  if (lane == 0) sm.r.ssh[wid] = sAw;
  __syncthreads();
  float4 v = make_float4(0.f, 0.f, 0.f, 0.f);
  #pragma unroll
  for (int ww = 0; ww < 4; ++ww) {
    float4 x = *(const float4*)&sm.r.nsh[ww * D + tid * 4];
    v.x += x.x; v.y += x.y; v.z += x.z; v.w += x.w;
  }
  *(float4*)(accOut + ((size_t)chunk * NB + b) * D + tid * 4) = v;
  if (tid == 0)
    sOut[chunk * NB + b] = sm.r.ssh[0] + sm.r.ssh[1] + sm.r.ssh[2] + sm.r.ssh[3];
}

extern "C" void kernel_launch(void* const* d_in, const int* in_sizes, int n_in,
                              void* d_out, int out_size, void* d_ws, size_t ws_size,
                              hipStream_t stream) {
  const float* ref    = (const float*)d_in[0];
  const float* cap    = (const float*)d_in[1];
  const float* tar    = (const float*)d_in[2];
  const float* qr_w   = (const float*)d_in[3];
  const float* qr_b   = (const float*)d_in[4];
  const float* ktxt_w = (const float*)d_in[5];
  const float* ktxt_b = (const float*)d_in[6];
  const float* ktar_w = (const float*)d_in[7];
  const float* ktar_b = (const float*)d_in[8];
  const float* v_w    = (const float*)d_in[9];
  const float* v_b    = (const float*)d_in[10];
  float* out = (float*)d_out;
  float* ws  = (float*)d_ws;

  // ws layout: big 32*PS (gemm partials), strm 8*PS, finals 6*PS, scalars.
  float* big  = ws;
  float* strm = ws + 32 * PS;
  float* q0   = ws + 40 * PS;
  float* p    = ws + 41 * PS;
  float* nacc = ws + 42 * PS;
  float* u    = ws + 43 * PS;
  float* w    = ws + 44 * PS;
  float* accT = ws + 45 * PS;
  float* sAP  = ws + 46 * PS;        // [8][128]
  float* sA   = sAP + 1024;          // [128]
  float* ZP   = sA + 128;            // [8][128]
  float* Z    = ZP + 1024;           // [128]

  const dim3 bG(256);
  const dim3 gGemm(NTILE), gR32(128), gR8(129), gStrm(NTILE);

  // q0 = ref[:,0,:] @ qr_w^T + qr_b
  gemm_k<0, 1, 0><<<gGemm, bG, 0, stream>>>(ref, (size_t)LSEQ * D, qr_w, qr_b, nullptr, big);
  reduce32_k<<<gR32, bG, 0, stream>>>(big, q0);
  // p = q0 @ ktxt_w
  gemm_k<1, 0, 0><<<gGemm, bG, 0, stream>>>(q0, D, ktxt_w, nullptr, nullptr, big);
  reduce32_k<<<gR32, bG, 0, stream>>>(big, p);
  // caption stream -> strm partials, sAP
  stream_k<0><<<gStrm, bG, 0, stream>>>(cap, p, q0, ktxt_b, strm, sAP);
  reduce8_k<<<gR8, bG, 0, stream>>>(strm, nacc, sAP, sA);
  // u = nacc @ ktxt_w^T + sA*ktxt_b
  gemm_k<0, 2, 0><<<gGemm, bG, 0, stream>>>(nacc, D, ktxt_w, ktxt_b, sA, big);
  reduce32_k<<<gR32, bG, 0, stream>>>(big, u);
  // w = u @ ktar_w
  gemm_k<1, 0, 0><<<gGemm, bG, 0, stream>>>(u, D, ktar_w, nullptr, nullptr, big);
  reduce32_k<<<gR32, bG, 0, stream>>>(big, w);
  // target stream -> strm partials, ZP
  stream_k<1><<<gStrm, bG, 0, stream>>>(tar, w, u, ktar_b, strm, ZP);
  reduce8_k<<<gR8, bG, 0, stream>>>(strm, accT, ZP, Z);
  // out = (accT/Z) @ v_w^T + v_b
  gemm_k<0, 1, 1><<<gGemm, bG, 0, stream>>>(accT, D, v_w, v_b, Z, big);
  reduce32_k<<<gR32, bG, 0, stream>>>(big, out);
}